// Round 3
// baseline (3168.679 us; speedup 1.0000x reference)
//
#include <hip/hip_runtime.h>
#include <stdint.h>

// Problem constants
#define Bsz  64
#define Tsz  512
#define NUsz 256
#define NXsz 1024

// Decomposition: 8 groups x 8 batches; 32 WGs per group, 32 columns each.
// Grouping is plain blockIdx arithmetic (g = bx & 7 aligns with the usual
// round-robin XCD dispatch as a *performance* heuristic only); ALL cross-WG
// comm is agent-scope (LLC) exactly like the verified round-0 kernel, so
// correctness does not depend on placement.
#define NGRP 8
#define GWG  32
#define MB   8
#define NC   32

// Sticky watchdog: legit waits are ~1e2..1e3 polls. If a wait exceeds
// SPIN_MAX polls, trip permanently (skip all future waits) so the kernel
// terminates fast with wrong data + counters instead of hanging the harness.
#define SPIN_MAX (1u << 18)

typedef __attribute__((ext_vector_type(8))) short  short8;
typedef __attribute__((ext_vector_type(4))) float  float4v;
typedef unsigned long long ull;

// Workspace layout (d_ws)
#define FLAGX_OFF   0        // 8 groups x 32 u32
#define FLAGFX_OFF  2048     // 8 groups x 32 u32
#define XBUF_OFF    4096     // 8 x 32768
#define XBUF_PG     32768    // per group: 2 parities x 16 KB (8 rows x 1024 cols bf16)
#define FXBUF_OFF   (XBUF_OFF + NGRP * XBUF_PG)   // 266240
// total ws use: 266240 + 8*32768 = 528384 bytes (same as round-0 kernel)

__device__ __forceinline__ short f2bf(float f) {
  unsigned x = __float_as_uint(f);
  return (short)((x + 0x7fffu + ((x >> 16) & 1u)) >> 16);  // RNE f32->bf16
}

// Init: set flags, stage x0 (bf16) into parity-0 x buffers. Plain stores:
// end-of-kernel L2 writeback makes them LLC-visible before gru_persist's
// agent-scope loads run (verified pattern from the round-0 kernel).
__global__ void gru_init(const float* __restrict__ x0, unsigned char* __restrict__ ws) {
  unsigned idx = blockIdx.x * 256u + threadIdx.x;   // 65536 total
  if (idx < 256u)      ((unsigned*)(ws + FLAGX_OFF))[idx] = 1u;         // x_0 ready
  else if (idx < 512u) ((unsigned*)(ws + FLAGFX_OFF))[idx - 256u] = 0u;
  unsigned g = idx >> 13, c = (idx >> 8) & 31u, b = (idx >> 5) & 7u, cc = idx & 31u;
  float v = x0[(g * MB + b) * NXsz + c * 32u + cc];
  *(short*)(ws + XBUF_OFF + g * XBUF_PG + c * 512u + b * 64u + cc * 2u) = f2bf(v);
}

// Poll 32 flags with relaxed agent-scope loads (LLC-coherent).
__device__ __forceinline__ void wait_flags(const unsigned* f, int lane, unsigned need,
                                           unsigned* dead) {
  if (*dead) return;
  const unsigned* p = f + (lane & 31);
  unsigned spins = 0;
  while (true) {
    unsigned v = __hip_atomic_load(p, __ATOMIC_RELAXED, __HIP_MEMORY_SCOPE_AGENT);
    if (__all((int)(v >= need))) break;
    if (++spins > SPIN_MAX) { *dead = 1u; break; }   // sticky trip
    __builtin_amdgcn_s_sleep(1);
  }
  // Compiler barrier + waitcnt only (data loads are agent-scope themselves).
  __builtin_amdgcn_fence(__ATOMIC_ACQUIRE, "workgroup");
}

// Load one B-fragment (16 cols starting at `col`, K rows k0..k0+7) from a
// row-major [K][NX] fp32 matrix into a bf16 short8. One-time init cost.
__device__ __forceinline__ short8 ldfragB(const float* __restrict__ U, int col, int k0) {
  short8 s;
  #pragma unroll
  for (int e = 0; e < 8; ++e) s[e] = f2bf(U[(long)(k0 + e) * NXsz + col]);
  return s;
}

#define MFMA(a, b, c) __builtin_amdgcn_mfma_f32_16x16x32_bf16((a), (b), (c), 0, 0, 0)

__launch_bounds__(256, 1)
__global__ void gru_persist(const float* __restrict__ u,  const float* __restrict__ x0,
                            const float* __restrict__ Wz, const float* __restrict__ Uz, const float* __restrict__ bz,
                            const float* __restrict__ Wf, const float* __restrict__ Uf, const float* __restrict__ bfp,
                            const float* __restrict__ Wr, const float* __restrict__ Ur, const float* __restrict__ br,
                            float* __restrict__ out, unsigned char* __restrict__ ws)
{
  // LDS: z/f U-slabs (K chunks 0..30; chunk 31 + all W slabs + full Ur share
  // live in registers -- 3 gates x 32 cols would not fit in 160 KiB).
  __shared__ short zfU[2][32][1000];           // 128,000 B (stride 2000 B, 16B-aligned)
  __shared__ float part[4][2][8][33];          //   8,448 B (padded: avoids 8-way conflicts)
  __shared__ float xs[8][33];                  //   1,056 B fp32 carried state (padded)
  __shared__ float bz_s[32], bf_s[32], br_s[32];
  // total ~137.9 KB => 1 WG/CU

  const int bx   = blockIdx.x;
  const int g    = bx & 7;                     // group
  const int rank = bx >> 3;                    // 0..31 within group
  const int col0 = rank * NC;
  const int tid  = threadIdx.x;
  const int wv   = tid >> 6;
  const int lane = tid & 63;
  const int q    = lane >> 4;
  const int cl   = lane & 15;

  // --- stage z/f U column slabs (K 0..991) to LDS, bf16 ---
  for (int idx = tid; idx < 2 * 32 * 992; idx += 256) {
    int gate = (idx >= 32 * 992);
    int rem  = idx - gate * (32 * 992);
    int k = rem >> 5, n = rem & 31;
    const float* U = gate ? Uf : Uz;
    zfU[gate][n][k] = f2bf(U[(long)k * NXsz + col0 + n]);
  }
  { int b = tid >> 5, n = tid & 31;
    xs[b][n] = x0[(g * MB + b) * NXsz + col0 + n]; }
  if (tid < 32) {
    bz_s[tid] = bz[col0 + tid];
    bf_s[tid] = bfp[col0 + tid];
    br_s[tid] = br[col0 + tid];
  }

  // --- per-wave register weights: full Ur share, all W slabs, zf chunk 31 ---
  const int bc0 = col0 + cl;
  short8 rU[16], rW[4], zW[4], fW[4], zU31[2], fU31[2];
  #pragma unroll
  for (int i = 0; i < 8; ++i) {
    int k0 = (wv * 8 + i) * 32 + q * 8;
    rU[i*2+0] = ldfragB(Ur, bc0,      k0);
    rU[i*2+1] = ldfragB(Ur, bc0 + 16, k0);
  }
  #pragma unroll
  for (int i = 0; i < 2; ++i) {
    int k0 = (wv * 2 + i) * 32 + q * 8;
    rW[i*2+0] = ldfragB(Wr, bc0, k0);  rW[i*2+1] = ldfragB(Wr, bc0+16, k0);
    zW[i*2+0] = ldfragB(Wz, bc0, k0);  zW[i*2+1] = ldfragB(Wz, bc0+16, k0);
    fW[i*2+0] = ldfragB(Wf, bc0, k0);  fW[i*2+1] = ldfragB(Wf, bc0+16, k0);
  }
  if (wv == 3) {
    zU31[0] = ldfragB(Uz, bc0, 992 + q*8);  zU31[1] = ldfragB(Uz, bc0+16, 992 + q*8);
    fU31[0] = ldfragB(Uf, bc0, 992 + q*8);  fU31[1] = ldfragB(Uf, bc0+16, 992 + q*8);
  } else {
    #pragma unroll
    for (int e = 0; e < 8; ++e) { zU31[0][e]=0; zU31[1][e]=0; fU31[0][e]=0; fU31[1][e]=0; }
  }
  __syncthreads();

  unsigned* flagx  = (unsigned*)(ws + FLAGX_OFF)  + g * GWG;
  unsigned* flagfx = (unsigned*)(ws + FLAGFX_OFF) + g * GWG;
  unsigned char* xb_base  = ws + XBUF_OFF  + (unsigned)g * XBUF_PG;
  unsigned char* fxb_base = ws + FXBUF_OFF + (unsigned)g * XBUF_PG;

  // A-fragment: rows 0..7 are batches; lanes cl>=8 duplicate batch cl&7 --
  // their MFMA output rows (8..15) are never read.
  const int b8 = cl & 7;
  const unsigned arow = (unsigned)(b8 * 64 + q * 16);
  const float* u_row = u + (long)(g * MB + b8) * (Tsz * (long)NUsz);

  // combine / publish pattern: lane -> (row cb, 4 consecutive cols at cc0)
  const int cb  = lane >> 3;
  const int cc0 = (lane & 7) * 4;

  float zreg[4] = {0.f, 0.f, 0.f, 0.f};
  unsigned dead = 0;

  for (int t = 0; t < Tsz; ++t) {
    const unsigned char* xb  = xb_base  + (t & 1) * 16384;
    unsigned char*       fxb = fxb_base + (t & 1) * 16384;

    // out[b][t][cols] = x_t  (wave 2; xs stable: written by wave0 after s3,
    // read here after s4 of the previous step)
    if (wv == 2) {
      float4v o = { xs[cb][cc0], xs[cb][cc0+1], xs[cb][cc0+2], xs[cb][cc0+3] };
      *(float4v*)(out + (long)(g*MB+cb) * (Tsz*(long)NXsz) + (long)t*NXsz + col0 + cc0) = o;
    }

    // ---- flag-independent: u-projection fragments + W MFMAs (z,f) ----
    short8 au[2];
    #pragma unroll
    for (int i = 0; i < 2; ++i) {
      const float* up = u_row + (long)t * NUsz + (wv*2 + i) * 32 + q * 8;
      float4v a0 = *(const float4v*)up;
      float4v a1 = *(const float4v*)(up + 4);
      short8 s;
      s[0]=f2bf(a0[0]); s[1]=f2bf(a0[1]); s[2]=f2bf(a0[2]); s[3]=f2bf(a0[3]);
      s[4]=f2bf(a1[0]); s[5]=f2bf(a1[1]); s[6]=f2bf(a1[2]); s[7]=f2bf(a1[3]);
      au[i] = s;
    }
    float4v az0 = {0,0,0,0}, az1 = {0,0,0,0}, af0 = {0,0,0,0}, af1 = {0,0,0,0};
    #pragma unroll
    for (int i = 0; i < 2; ++i) {
      az0 = MFMA(au[i], zW[i*2+0], az0);
      az1 = MFMA(au[i], zW[i*2+1], az1);
      af0 = MFMA(au[i], fW[i*2+0], af0);
      af1 = MFMA(au[i], fW[i*2+1], af1);
    }

    // ---- phase 1: wait full x_t, accumulate x@Uz, x@Uf ----
    wait_flags(flagx, lane, (unsigned)(t + 1), &dead);
    {
      ull ax[16];
      #pragma unroll
      for (int i = 0; i < 8; ++i) {
        const ull* pp = (const ull*)(xb + arow + (unsigned)((wv*8 + i) * 512));
        ax[2*i]   = __hip_atomic_load(pp,     __ATOMIC_RELAXED, __HIP_MEMORY_SCOPE_AGENT);
        ax[2*i+1] = __hip_atomic_load(pp + 1, __ATOMIC_RELAXED, __HIP_MEMORY_SCOPE_AGENT);
      }
      #pragma unroll
      for (int i = 0; i < 8; ++i) {
        union { ull u2[2]; short8 s8; } cv;
        cv.u2[0] = ax[2*i]; cv.u2[1] = ax[2*i+1];
        const int c = wv*8 + i;
        int koff;
        short8 b00, b01, b10, b11;
        if (i == 7) {
          koff = ((wv == 3) ? 0 : c*32) + q*8;   // keep LDS index in-bounds
          b00 = *(const short8*)&zfU[0][cl][koff];
          b01 = *(const short8*)&zfU[0][cl+16][koff];
          b10 = *(const short8*)&zfU[1][cl][koff];
          b11 = *(const short8*)&zfU[1][cl+16][koff];
          if (wv == 3) { b00 = zU31[0]; b01 = zU31[1]; b10 = fU31[0]; b11 = fU31[1]; }
        } else {
          koff = c*32 + q*8;
          b00 = *(const short8*)&zfU[0][cl][koff];
          b01 = *(const short8*)&zfU[0][cl+16][koff];
          b10 = *(const short8*)&zfU[1][cl][koff];
          b11 = *(const short8*)&zfU[1][cl+16][koff];
        }
        az0 = MFMA(cv.s8, b00, az0);
        az1 = MFMA(cv.s8, b01, az1);
        af0 = MFMA(cv.s8, b10, af0);
        af1 = MFMA(cv.s8, b11, af1);
      }
    }

    if (q < 2) {
      #pragma unroll
      for (int r = 0; r < 4; ++r) {
        part[wv][0][q*4+r][cl]      = az0[r];
        part[wv][0][q*4+r][cl + 16] = az1[r];
        part[wv][1][q*4+r][cl]      = af0[r];
        part[wv][1][q*4+r][cl + 16] = af1[r];
      }
    }
    __syncthreads();  // s1

    if (wv == 0) {            // z gate -> registers
      #pragma unroll
      for (int j = 0; j < 4; ++j) {
        int c = cc0 + j;
        float s = part[0][0][cb][c] + part[1][0][cb][c] + part[2][0][cb][c] + part[3][0][cb][c] + bz_s[c];
        zreg[j] = 1.f / (1.f + __expf(-s));
      }
    } else if (wv == 1) {     // f gate -> publish f*x slice (one 8-B atomic per lane)
      ull pack = 0;
      #pragma unroll
      for (int j = 0; j < 4; ++j) {
        int c = cc0 + j;
        float s = part[0][1][cb][c] + part[1][1][cb][c] + part[2][1][cb][c] + part[3][1][cb][c] + bf_s[c];
        float f = 1.f / (1.f + __expf(-s));
        pack |= (ull)(unsigned short)f2bf(f * xs[cb][c]) << (16 * j);
      }
      __hip_atomic_store((ull*)(fxb + (unsigned)(rank * 512 + lane * 8)), pack,
                         __ATOMIC_RELAXED, __HIP_MEMORY_SCOPE_AGENT);
      __builtin_amdgcn_fence(__ATOMIC_RELEASE, "workgroup");  // drains vmcnt, no cache ops
      if (lane == 0)
        __hip_atomic_store(flagfx + rank, (unsigned)(t + 1),
                           __ATOMIC_RELAXED, __HIP_MEMORY_SCOPE_AGENT);
    }
    __syncthreads();  // s2

    // ---- phase 2: r = tanh(ar + (f.x)@Ur); x_next; publish x slice ----
    float4v ar0 = {0,0,0,0}, ar1 = {0,0,0,0};
    #pragma unroll
    for (int i = 0; i < 2; ++i) {
      ar0 = MFMA(au[i], rW[i*2+0], ar0);
      ar1 = MFMA(au[i], rW[i*2+1], ar1);
    }

    wait_flags(flagfx, lane, (unsigned)(t + 1), &dead);
    {
      ull ax[16];
      #pragma unroll
      for (int i = 0; i < 8; ++i) {
        const ull* pp = (const ull*)(fxb + arow + (unsigned)((wv*8 + i) * 512));
        ax[2*i]   = __hip_atomic_load(pp,     __ATOMIC_RELAXED, __HIP_MEMORY_SCOPE_AGENT);
        ax[2*i+1] = __hip_atomic_load(pp + 1, __ATOMIC_RELAXED, __HIP_MEMORY_SCOPE_AGENT);
      }
      #pragma unroll
      for (int i = 0; i < 8; ++i) {
        union { ull u2[2]; short8 s8; } cv;
        cv.u2[0] = ax[2*i]; cv.u2[1] = ax[2*i+1];
        ar0 = MFMA(cv.s8, rU[i*2+0], ar0);
        ar1 = MFMA(cv.s8, rU[i*2+1], ar1);
      }
    }

    if (q < 2) {
      #pragma unroll
      for (int r = 0; r < 4; ++r) {
        part[wv][0][q*4+r][cl]      = ar0[r];
        part[wv][0][q*4+r][cl + 16] = ar1[r];
      }
    }
    __syncthreads();  // s3

    if (wv == 0) {            // combine + publish x_{t+1}
      unsigned char* xbn = xb_base + ((t + 1) & 1) * 16384;
      ull pack = 0;
      float xnv[4];
      #pragma unroll
      for (int j = 0; j < 4; ++j) {
        int c = cc0 + j;
        float s = part[0][0][cb][c] + part[1][0][cb][c] + part[2][0][cb][c] + part[3][0][cb][c] + br_s[c];
        s = fminf(fmaxf(s, -15.f), 15.f);
        float e  = __expf(2.f * s);
        float rr = (e - 1.f) / (e + 1.f);            // tanh
        float xn = zreg[j] * xs[cb][c] + (1.f - zreg[j]) * rr;
        xnv[j] = xn;
        pack |= (ull)(unsigned short)f2bf(xn) << (16 * j);
      }
      #pragma unroll
      for (int j = 0; j < 4; ++j) xs[cb][cc0 + j] = xnv[j];
      __hip_atomic_store((ull*)(xbn + (unsigned)(rank * 512 + lane * 8)), pack,
                         __ATOMIC_RELAXED, __HIP_MEMORY_SCOPE_AGENT);
      __builtin_amdgcn_fence(__ATOMIC_RELEASE, "workgroup");
      if (lane == 0)
        __hip_atomic_store(flagx + rank, (unsigned)(t + 2),
                           __ATOMIC_RELAXED, __HIP_MEMORY_SCOPE_AGENT);
    }
    __syncthreads();  // s4
  }
}

extern "C" void kernel_launch(void* const* d_in, const int* in_sizes, int n_in,
                              void* d_out, int out_size, void* d_ws, size_t ws_size,
                              hipStream_t stream) {
  (void)in_sizes; (void)n_in; (void)out_size; (void)ws_size;
  const float* u   = (const float*)d_in[0];
  const float* x0  = (const float*)d_in[1];
  const float* Wz  = (const float*)d_in[2];
  const float* Uz  = (const float*)d_in[3];
  const float* bz  = (const float*)d_in[4];
  const float* Wf  = (const float*)d_in[5];
  const float* Uf  = (const float*)d_in[6];
  const float* bfp = (const float*)d_in[7];
  const float* Wr  = (const float*)d_in[8];
  const float* Ur  = (const float*)d_in[9];
  const float* br  = (const float*)d_in[10];
  float* out = (float*)d_out;
  unsigned char* ws = (unsigned char*)d_ws;

  hipLaunchKernelGGL(gru_init, dim3(256), dim3(256), 0, stream, x0, ws);

  void* args[] = { (void*)&u, (void*)&x0, (void*)&Wz, (void*)&Uz, (void*)&bz,
                   (void*)&Wf, (void*)&Uf, (void*)&bfp,
                   (void*)&Wr, (void*)&Ur, (void*)&br, (void*)&out, (void*)&ws };
  hipError_t e = hipLaunchCooperativeKernel((const void*)gru_persist, dim3(256), dim3(256),
                                            args, 0, stream);
  if (e != hipSuccess) {
    // Fallback: plain launch (1 WG/CU by LDS limit; 256 blocks co-resident)
    hipLaunchKernelGGL(gru_persist, dim3(256), dim3(256), 0, stream,
                       u, x0, Wz, Uz, bz, Wf, Uf, bfp, Wr, Ur, br, out, ws);
  }
}